// Round 3
// baseline (525.231 us; speedup 1.0000x reference)
//
#include <hip/hip_runtime.h>
#include <math.h>

// NoRefRetIQANet: cosine top-K retrieval via fp16 2-split MFMA.
//   score[b,n] = dot(q_b, d_n) / ||d_n||  (query norm skipped: order-invariant)
//   x = hi + lo/4096;  dot = hh + (hl + lh)/4096  (ll term ~2^-24, dropped)
// Round-3 structure: BN=32 -> 1875 uniform blocks (7.3/CU), 128 thr,
// wave tile 32q x 32n, 2-step-deep register pipeline, swizzled A-pack so
// A staging is a straight coalesced copy and all LDS ops are bank-uniform.
// ws: semp0[64][20000] f32, semp1, dstp, nsq0/1/d[20000], apack_sem, apack_dst
// d_out: [0,64) result, [64, 64+64*18) retrieved.

typedef _Float16 half8 __attribute__((ext_vector_type(8)));
typedef float    f32x4 __attribute__((ext_vector_type(4)));

#define NDB   20000
#define NQ    64
#define KSEM  4096
#define KDST  2048
#define KC    2048
#define NSTEP (KC / 32)     // 64
#define BN    32
#define NTILE (NDB / BN)    // 625 exact, no tail

// ---------------------------------------------------------------------------
// qsplit: fp32 queries -> fragment-ordered, bank-swizzled f16 hi/lo pack.
// Pack unit u (16B = half8) within a 32-k step: u = 4*row + (((row>>1)&3)^kg)
// step section = 512 units: [0,256) hi, [256,512) lo.
// ---------------------------------------------------------------------------
__global__ __launch_bounds__(256) void qsplit_kernel(
    const float* __restrict__ fc, const float* __restrict__ fd,
    _Float16* __restrict__ apack_sem, _Float16* __restrict__ apack_dst)
{
    const int idx = (int)blockIdx.x * 256 + (int)threadIdx.x;
    const int NSEM8 = NQ * KSEM / 8;            // 32768
    const float* src; _Float16* dst; int row, g8, K;
    if (idx < NSEM8) { src = fc; dst = apack_sem; K = KSEM; row = idx >> 9; g8 = idx & 511; }
    else { const int j = idx - NSEM8; src = fd; dst = apack_dst; K = KDST; row = j >> 8; g8 = j & 255; }

    const float* p = src + (size_t)row * K + g8 * 8;
    const float4 v0 = ((const float4*)p)[0];
    const float4 v1 = ((const float4*)p)[1];
    const float xs[8] = {v0.x, v0.y, v0.z, v0.w, v1.x, v1.y, v1.z, v1.w};
    half8 hi, lo;
    #pragma unroll
    for (int e = 0; e < 8; ++e) {
        const _Float16 h = (_Float16)xs[e];
        hi[e] = h;
        lo[e] = (_Float16)((xs[e] - (float)h) * 4096.0f);   // residual exact in f32
    }
    const int step = g8 >> 2, kg = g8 & 3;
    const int u = (row << 2) + (((row >> 1) & 3) ^ kg);
    half8* d8 = (half8*)dst;
    d8[step * 512 + u]       = hi;
    d8[step * 512 + 256 + u] = lo;
}

// ---------------------------------------------------------------------------
// score: 1875 blocks = 625 n-tiles x {sem kc0, sem kc1, dst}, uniform KC=2048.
// Block 128 thr / 2 waves; wave w computes rows [w*32, w*32+32) x all 32 cols.
// A staged as straight copy of swizzled pack; B staged f32->hi/lo at write.
// 2-deep reg pipeline: loads for s+2/s+3 issued one full phase before use.
// ---------------------------------------------------------------------------
__global__ __launch_bounds__(128, 3) void score_kernel(
    const float* __restrict__ sdb, const float* __restrict__ ddb,
    const _Float16* __restrict__ apack_sem, const _Float16* __restrict__ apack_dst,
    float* __restrict__ semp0, float* __restrict__ semp1, float* __restrict__ dstp,
    float* __restrict__ nsq0, float* __restrict__ nsq1, float* __restrict__ nsqd)
{
    __shared__ __align__(16) _Float16 A_lds[2][4096];        // [buf][split|row|k] 16 KB
    __shared__ __align__(16) _Float16 B_lds[2][2][BN][40];   // 10 KB, stride 5x16B (odd)

    const int tid = threadIdx.x;
    const int bid = (int)blockIdx.x;
    const int mkc = bid / NTILE;          // 0: sem kc0, 1: sem kc1, 2: dst
    const int nt  = bid % NTILE;
    const int n0  = nt * BN;

    const float* D; const _Float16* AP; float *SOUT, *NOUT; int Ks, koff;
    if (mkc == 0)      { D=sdb; AP=apack_sem; SOUT=semp0; NOUT=nsq0; Ks=KSEM; koff=0;  }
    else if (mkc == 1) { D=sdb; AP=apack_sem; SOUT=semp1; NOUT=nsq1; Ks=KSEM; koff=KC; }
    else               { D=ddb; AP=apack_dst; SOUT=dstp;  NOUT=nsqd; Ks=KDST; koff=0;  }

    // B staging map: thread -> (row srow 0..31, 8-float slice sq4 0..3)
    const int srow = tid >> 2, sq4 = tid & 3;
    const float* bsrc = D + (size_t)(n0 + srow) * Ks + koff + sq4 * 8;
    // A staging: pack already in LDS order; thread copies units {tid+128c}
    const uint4* asrc = (const uint4*)AP + (size_t)(koff >> 5) * 512;

    // compute map
    const int l = tid & 63, w = tid >> 6;
    const int lr = l & 15, kg = l >> 4;

    f32x4 acc_h[2][2], acc_x[2][2];
    const f32x4 zz = {0.f, 0.f, 0.f, 0.f};
    #pragma unroll
    for (int i = 0; i < 2; ++i)
        #pragma unroll
        for (int j = 0; j < 2; ++j) { acc_h[i][j] = zz; acc_x[i][j] = zz; }
    float sq = 0.f;

    auto LOADR = [&](int s, uint4* a, float4& b0, float4& b1) {
        const uint4* ap = asrc + (size_t)s * 512 + tid;
        a[0] = ap[0]; a[1] = ap[128]; a[2] = ap[256]; a[3] = ap[384];
        const float* bp = bsrc + (size_t)s * 32;
        b0 = ((const float4*)bp)[0];
        b1 = ((const float4*)bp)[1];
    };

    auto WRITE = [&](int buf, const uint4* a, const float4& b0, const float4& b1) {
        uint4* al = (uint4*)A_lds[buf] + tid;
        al[0] = a[0]; al[128] = a[1]; al[256] = a[2]; al[384] = a[3];
        const float xs[8] = {b0.x, b0.y, b0.z, b0.w, b1.x, b1.y, b1.z, b1.w};
        half8 hi, lo;
        float s2 = 0.f;
        #pragma unroll
        for (int e = 0; e < 8; ++e) {
            const float x = xs[e];
            s2 = fmaf(x, x, s2);
            const _Float16 h = (_Float16)x;
            hi[e] = h;
            lo[e] = (_Float16)((x - (float)h) * 4096.0f);
        }
        sq += s2;
        *(half8*)&B_lds[buf][0][srow][sq4 * 8] = hi;
        *(half8*)&B_lds[buf][1][srow][sq4 * 8] = lo;
    };

    auto COMPUTE = [&](int buf) {
        half8 bh[2], bl[2], ah[2], av[2];
        #pragma unroll
        for (int j = 0; j < 2; ++j) {
            const int col = j * 16 + lr;
            bh[j] = *(const half8*)&B_lds[buf][0][col][kg * 8];
            bl[j] = *(const half8*)&B_lds[buf][1][col][kg * 8];
        }
        #pragma unroll
        for (int i = 0; i < 2; ++i) {
            const int row = w * 32 + i * 16 + lr;
            const int u = (row << 2) + (((row >> 1) & 3) ^ kg);
            ah[i] = *((const half8*)A_lds[buf] + u);
            av[i] = *((const half8*)A_lds[buf] + 256 + u);
        }
        #pragma unroll
        for (int i = 0; i < 2; ++i)
            #pragma unroll
            for (int j = 0; j < 2; ++j) {
                acc_h[i][j] = __builtin_amdgcn_mfma_f32_16x16x32_f16(ah[i], bh[j], acc_h[i][j], 0, 0, 0);
                acc_x[i][j] = __builtin_amdgcn_mfma_f32_16x16x32_f16(ah[i], bl[j], acc_x[i][j], 0, 0, 0);
                acc_x[i][j] = __builtin_amdgcn_mfma_f32_16x16x32_f16(av[i], bh[j], acc_x[i][j], 0, 0, 0);
            }
    };

    uint4 aP[4], aQ[4]; float4 bP0, bP1, bQ0, bQ1;
    LOADR(0, aP, bP0, bP1);
    WRITE(0, aP, bP0, bP1);
    LOADR(1, aQ, bQ0, bQ1);
    __syncthreads();

    for (int s = 0; s < NSTEP; s += 2) {
        if (s + 2 < NSTEP) LOADR(s + 2, aP, bP0, bP1);
        COMPUTE(0);                    // step s
        WRITE(1, aQ, bQ0, bQ1);        // step s+1 data (issued one phase ago)
        __syncthreads();
        if (s + 3 < NSTEP) LOADR(s + 3, aQ, bQ0, bQ1);
        COMPUTE(1);                    // step s+1
        if (s + 2 < NSTEP) WRITE(0, aP, bP0, bP1);
        __syncthreads();
    }

    // norm partials: 4 lanes (sq4) cover one DB row's chunk
    float sqt = sq + __shfl_xor(sq, 1);
    sqt += __shfl_xor(sqt, 2);
    if (sq4 == 0) NOUT[n0 + srow] = sqt;

    // C/D map: col=lane&15, row=(lane>>4)*4+reg (m89-verified)
    #pragma unroll
    for (int i = 0; i < 2; ++i)
        #pragma unroll
        for (int j = 0; j < 2; ++j) {
            const int n = n0 + j * 16 + lr;
            #pragma unroll
            for (int rr = 0; rr < 4; ++rr) {
                const int q = w * 32 + i * 16 + kg * 4 + rr;
                SOUT[(size_t)q * NDB + n] = acc_h[i][j][rr] + acc_x[i][j][rr] * (1.0f / 4096.0f);
            }
        }
}

// ---------------------------------------------------------------------------
// Top-9 per (matrix m, row b); combines sem partials, applies 1/||d_n||.
// Comparator: value desc, index asc (matches lax.top_k).
// ---------------------------------------------------------------------------
__global__ __launch_bounds__(256) void topk_kernel(
    const float* __restrict__ semp0, const float* __restrict__ semp1,
    const float* __restrict__ dstp,
    const float* __restrict__ nsq0, const float* __restrict__ nsq1,
    const float* __restrict__ nsqd,
    const float* __restrict__ metrics, float* __restrict__ out_ret)
{
    __shared__ float sv[256][9];
    __shared__ int   si[256][9];

    const int tid = threadIdx.x;
    const int b = (int)blockIdx.x & 63;
    const int m = (int)blockIdx.x >> 6;   // 0=sem, 1=dst

    float v[9]; int ix[9];
    #pragma unroll
    for (int k = 0; k < 9; ++k) { v[k] = -INFINITY; ix[k] = 0x7fffffff; }

    const size_t roff = (size_t)b * NDB;
    for (int i = tid; i < NDB; i += 256) {
        float sval;
        if (m == 0) {
            const float s = semp0[roff + i] + semp1[roff + i];
            sval = s * (1.0f / sqrtf(nsq0[i] + nsq1[i]));
        } else {
            sval = dstp[roff + i] * (1.0f / sqrtf(nsqd[i]));
        }
        if (sval > v[0]) {
            bool bt[9];
            bt[0] = true;
            #pragma unroll
            for (int j = 1; j < 9; ++j) bt[j] = sval > v[j];
            #pragma unroll
            for (int j = 0; j < 8; ++j) {
                v[j]  = bt[j+1] ? v[j+1]  : (bt[j] ? sval : v[j]);
                ix[j] = bt[j+1] ? ix[j+1] : (bt[j] ? i    : ix[j]);
            }
            v[8]  = bt[8] ? sval : v[8];
            ix[8] = bt[8] ? i    : ix[8];
        }
    }

    #pragma unroll
    for (int k = 0; k < 9; ++k) { sv[tid][k] = v[k]; si[tid][k] = ix[k]; }
    __syncthreads();

    for (int s2 = 128; s2 >= 1; s2 >>= 1) {
        if (tid < s2) {
            float rv[9]; int ri[9];
            int pa = 8, pb = 8;
            #pragma unroll
            for (int k = 8; k >= 0; --k) {
                const float va = sv[tid][pa];      const int ia = si[tid][pa];
                const float vb = sv[tid + s2][pb]; const int ib = si[tid + s2][pb];
                const bool takeA = (va > vb) || (va == vb && ia < ib);
                rv[k] = takeA ? va : vb;
                ri[k] = takeA ? ia : ib;
                if (takeA) --pa; else --pb;
            }
            #pragma unroll
            for (int k = 0; k < 9; ++k) { sv[tid][k] = rv[k]; si[tid][k] = ri[k]; }
        }
        __syncthreads();
    }

    if (tid < 9) {
        const int idx = si[0][8 - tid];
        out_ret[(size_t)b * 18 + 2 * tid + m] = metrics[idx];
    }
}

__global__ void finalize_kernel(float* __restrict__ d_out)
{
    const int b = threadIdx.x;
    const float* r = d_out + 64 + (size_t)b * 18;
    float s = 0.f;
    #pragma unroll
    for (int j = 0; j < 18; ++j) s += r[j];
    d_out[b] = s * (1.0f / 18.0f);
}

extern "C" void kernel_launch(void* const* d_in, const int* in_sizes, int n_in,
                              void* d_out, int out_size, void* d_ws, size_t ws_size,
                              hipStream_t stream)
{
    const float* fc  = (const float*)d_in[0];   // [64][4096]
    const float* fd  = (const float*)d_in[1];   // [64][2048]
    const float* sdb = (const float*)d_in[2];   // [20000][4096]
    const float* ddb = (const float*)d_in[3];   // [20000][2048]
    const float* met = (const float*)d_in[4];   // [20000]

    float* semp0 = (float*)d_ws;
    float* semp1 = semp0 + (size_t)NQ * NDB;
    float* dstp  = semp1 + (size_t)NQ * NDB;
    float* nsq0  = dstp  + (size_t)NQ * NDB;
    float* nsq1  = nsq0 + NDB;
    float* nsqd  = nsq1 + NDB;
    _Float16* apack_sem = (_Float16*)(nsqd + NDB);           // 64*4096*2 halves
    _Float16* apack_dst = apack_sem + (size_t)NQ * KSEM * 2; // 64*2048*2 halves

    float* out = (float*)d_out;

    qsplit_kernel<<<dim3(192), dim3(256), 0, stream>>>(fc, fd, apack_sem, apack_dst);
    score_kernel<<<dim3(3 * NTILE), dim3(128), 0, stream>>>(
        sdb, ddb, apack_sem, apack_dst, semp0, semp1, dstp, nsq0, nsq1, nsqd);
    topk_kernel<<<dim3(128), dim3(256), 0, stream>>>(
        semp0, semp1, dstp, nsq0, nsq1, nsqd, met, out + 64);
    finalize_kernel<<<dim3(1), dim3(64), 0, stream>>>(out);
}

// Round 4
// 269.500 us; speedup vs baseline: 1.9489x; 1.9489x over previous
//
#include <hip/hip_runtime.h>
#include <math.h>

// NoRefRetIQANet: cosine top-K retrieval via fp16 2-split MFMA.
//   score[b,n] = dot(q_b, d_n) / ||d_n||  (query norm skipped: order-invariant)
//   x = hi + lo/4096;  dot = hh + (hl + lh)/4096  (ll term ~2^-24, dropped)
// Round-4: BN=32 (1875 uniform blocks, 7.3/CU), 128 thr, single-ahead
// pipeline (no 2-deep reg sets -> no spills), A staged via global_load_lds
// from the pre-swizzled pack (linear LDS dest, zero staging VGPRs), B in a
// flat XOR-swizzled unit layout (same involution on write and read).
// ws: semp0[64][20000] f32, semp1, dstp, nsq0/1/d[20000], apack_sem, apack_dst
// d_out: [0,64) result, [64, 64+64*18) retrieved.

typedef _Float16 half8 __attribute__((ext_vector_type(8)));
typedef float    f32x4 __attribute__((ext_vector_type(4)));

#define NDB   20000
#define NQ    64
#define KSEM  4096
#define KDST  2048
#define KC    2048
#define NSTEP (KC / 32)     // 64
#define BN    32
#define NTILE (NDB / BN)    // 625 exact, no tail

__device__ __forceinline__ void async_cp16(const void* g, void* l) {
    __builtin_amdgcn_global_load_lds(
        (const __attribute__((address_space(1))) void*)g,
        (__attribute__((address_space(3))) void*)l, 16, 0, 0);
}

// ---------------------------------------------------------------------------
// qsplit: fp32 queries -> fragment-ordered, bank-swizzled f16 hi/lo pack.
// Unit u (16B = half8) within a 32-k step: u = 4*row + (((row>>1)&3)^kg);
// step section = 512 units: [0,256) hi, [256,512) lo.  (verified round 3)
// ---------------------------------------------------------------------------
__global__ __launch_bounds__(256) void qsplit_kernel(
    const float* __restrict__ fc, const float* __restrict__ fd,
    _Float16* __restrict__ apack_sem, _Float16* __restrict__ apack_dst)
{
    const int idx = (int)blockIdx.x * 256 + (int)threadIdx.x;
    const int NSEM8 = NQ * KSEM / 8;            // 32768
    const float* src; _Float16* dst; int row, g8, K;
    if (idx < NSEM8) { src = fc; dst = apack_sem; K = KSEM; row = idx >> 9; g8 = idx & 511; }
    else { const int j = idx - NSEM8; src = fd; dst = apack_dst; K = KDST; row = j >> 8; g8 = j & 255; }

    const float* p = src + (size_t)row * K + g8 * 8;
    const float4 v0 = ((const float4*)p)[0];
    const float4 v1 = ((const float4*)p)[1];
    const float xs[8] = {v0.x, v0.y, v0.z, v0.w, v1.x, v1.y, v1.z, v1.w};
    half8 hi, lo;
    #pragma unroll
    for (int e = 0; e < 8; ++e) {
        const _Float16 h = (_Float16)xs[e];
        hi[e] = h;
        lo[e] = (_Float16)((xs[e] - (float)h) * 4096.0f);
    }
    const int step = g8 >> 2, kg = g8 & 3;
    const int u = (row << 2) + (((row >> 1) & 3) ^ kg);
    half8* d8 = (half8*)dst;
    d8[step * 512 + u]       = hi;
    d8[step * 512 + 256 + u] = lo;
}

// ---------------------------------------------------------------------------
// score: 1875 blocks = 625 n-tiles x {sem kc0, sem kc1, dst}, uniform KC=2048.
// Block 128 thr / 2 waves; wave w computes q-rows [w*32, w*32+32) x 32 cols.
// ---------------------------------------------------------------------------
__global__ __launch_bounds__(128, 4) void score_kernel(
    const float* __restrict__ sdb, const float* __restrict__ ddb,
    const _Float16* __restrict__ apack_sem, const _Float16* __restrict__ apack_dst,
    float* __restrict__ semp0, float* __restrict__ semp1, float* __restrict__ dstp,
    float* __restrict__ nsq0, float* __restrict__ nsq1, float* __restrict__ nsqd)
{
    __shared__ __align__(16) _Float16 A_lds[2][4096];   // 2 x 512 units, 16 KB
    __shared__ __align__(16) _Float16 B_lds[2][2][1024];// 2 x (hi,lo) x 128 units, 8 KB

    const int tid = threadIdx.x;
    const int bid = (int)blockIdx.x;
    const int mkc = bid / NTILE;          // 0: sem kc0, 1: sem kc1, 2: dst
    const int nt  = bid % NTILE;
    const int n0  = nt * BN;

    const float* D; const _Float16* AP; float *SOUT, *NOUT; int Ks, koff;
    if (mkc == 0)      { D=sdb; AP=apack_sem; SOUT=semp0; NOUT=nsq0; Ks=KSEM; koff=0;  }
    else if (mkc == 1) { D=sdb; AP=apack_sem; SOUT=semp1; NOUT=nsq1; Ks=KSEM; koff=KC; }
    else               { D=ddb; AP=apack_dst; SOUT=dstp;  NOUT=nsqd; Ks=KDST; koff=0;  }

    // B staging map: thread -> (row srow 0..31, k-quad sq4 0..3: 8 floats)
    const int srow = tid >> 2, sq4 = tid & 3;
    const float* bsrc = D + (size_t)(n0 + srow) * Ks + koff + sq4 * 8;
    // A staging: DMA pack units; per-lane global src, wave-uniform LDS base
    const int lane = tid & 63, w = tid >> 6;
    const uint4* asrc = (const uint4*)AP + ((size_t)koff >> 5) * 512 + w * 256 + lane;

    // compute map
    const int lr = lane & 15, kg = lane >> 4;

    f32x4 acc_h[2][2], acc_x[2][2];
    const f32x4 zz = {0.f, 0.f, 0.f, 0.f};
    #pragma unroll
    for (int i = 0; i < 2; ++i)
        #pragma unroll
        for (int j = 0; j < 2; ++j) { acc_h[i][j] = zz; acc_x[i][j] = zz; }
    float sq = 0.f;

    auto ISSUE_A = [&](int s, int buf) {
        const uint4* g = asrc + (size_t)s * 512;
        _Float16* lb = &A_lds[buf][w * 2048];       // unit w*256
        async_cp16(g,       lb);
        async_cp16(g + 64,  lb + 512);
        async_cp16(g + 128, lb + 1024);
        async_cp16(g + 192, lb + 1536);
    };

    auto COMPUTE = [&](int buf) {
        half8 bh[2], bl[2];
        #pragma unroll
        for (int j = 0; j < 2; ++j) {
            const int col = j * 16 + lr;
            const int u = (col << 2) + (((col >> 1) & 3) ^ kg);
            bh[j] = *((const half8*)&B_lds[buf][0][0] + u);
            bl[j] = *((const half8*)&B_lds[buf][1][0] + u);
        }
        #pragma unroll
        for (int i = 0; i < 2; ++i) {
            const int row = w * 32 + i * 16 + lr;
            const int u = (row << 2) + (((row >> 1) & 3) ^ kg);
            const half8 ah = *((const half8*)&A_lds[buf][0] + u);
            const half8 av = *((const half8*)&A_lds[buf][0] + 256 + u);
            #pragma unroll
            for (int j = 0; j < 2; ++j) {
                acc_h[i][j] = __builtin_amdgcn_mfma_f32_16x16x32_f16(ah, bh[j], acc_h[i][j], 0, 0, 0);
                acc_x[i][j] = __builtin_amdgcn_mfma_f32_16x16x32_f16(ah, bl[j], acc_x[i][j], 0, 0, 0);
                acc_x[i][j] = __builtin_amdgcn_mfma_f32_16x16x32_f16(av, bh[j], acc_x[i][j], 0, 0, 0);
            }
        }
    };

    // prologue: stage step 0
    ISSUE_A(0, 0);
    {
        const float4 b0 = ((const float4*)bsrc)[0];
        const float4 b1 = ((const float4*)bsrc)[1];
        const float xs[8] = {b0.x, b0.y, b0.z, b0.w, b1.x, b1.y, b1.z, b1.w};
        half8 hi, lo; float s2 = 0.f;
        #pragma unroll
        for (int e = 0; e < 8; ++e) {
            const float x = xs[e];
            s2 = fmaf(x, x, s2);
            const _Float16 h = (_Float16)x;
            hi[e] = h;
            lo[e] = (_Float16)((x - (float)h) * 4096.0f);
        }
        sq += s2;
        const int ub = (srow << 2) + (((srow >> 1) & 3) ^ sq4);
        *((half8*)&B_lds[0][0][0] + ub) = hi;
        *((half8*)&B_lds[0][1][0] + ub) = lo;
    }
    __syncthreads();

    for (int s = 0; s < NSTEP - 1; ++s) {
        const int buf = s & 1, nbuf = buf ^ 1;
        ISSUE_A(s + 1, nbuf);                          // DMA, lands by barrier
        const float* bp = bsrc + (size_t)(s + 1) * 32;
        const float4 b0 = ((const float4*)bp)[0];      // in flight over COMPUTE
        const float4 b1 = ((const float4*)bp)[1];
        COMPUTE(buf);
        {
            const float xs[8] = {b0.x, b0.y, b0.z, b0.w, b1.x, b1.y, b1.z, b1.w};
            half8 hi, lo; float s2 = 0.f;
            #pragma unroll
            for (int e = 0; e < 8; ++e) {
                const float x = xs[e];
                s2 = fmaf(x, x, s2);
                const _Float16 h = (_Float16)x;
                hi[e] = h;
                lo[e] = (_Float16)((x - (float)h) * 4096.0f);
            }
            sq += s2;
            const int ub = (srow << 2) + (((srow >> 1) & 3) ^ sq4);
            *((half8*)&B_lds[nbuf][0][0] + ub) = hi;
            *((half8*)&B_lds[nbuf][1][0] + ub) = lo;
        }
        __syncthreads();
    }
    COMPUTE((NSTEP - 1) & 1);

    // norm partials: 4 lanes (sq4) cover one DB row's k-chunk
    float sqt = sq + __shfl_xor(sq, 1);
    sqt += __shfl_xor(sqt, 2);
    if (sq4 == 0) NOUT[n0 + srow] = sqt;

    // C/D map: col=lane&15, row=(lane>>4)*4+reg (m89-verified)
    #pragma unroll
    for (int i = 0; i < 2; ++i)
        #pragma unroll
        for (int j = 0; j < 2; ++j) {
            const int n = n0 + j * 16 + lr;
            #pragma unroll
            for (int rr = 0; rr < 4; ++rr) {
                const int q = w * 32 + i * 16 + kg * 4 + rr;
                SOUT[(size_t)q * NDB + n] = acc_h[i][j][rr] + acc_x[i][j][rr] * (1.0f / 4096.0f);
            }
        }
}

// ---------------------------------------------------------------------------
// Top-9 per (matrix m, row b); combines sem partials, applies 1/||d_n||.
// Comparator: value desc, index asc (matches lax.top_k).
// ---------------------------------------------------------------------------
__global__ __launch_bounds__(256) void topk_kernel(
    const float* __restrict__ semp0, const float* __restrict__ semp1,
    const float* __restrict__ dstp,
    const float* __restrict__ nsq0, const float* __restrict__ nsq1,
    const float* __restrict__ nsqd,
    const float* __restrict__ metrics, float* __restrict__ out_ret)
{
    __shared__ float sv[256][9];
    __shared__ int   si[256][9];

    const int tid = threadIdx.x;
    const int b = (int)blockIdx.x & 63;
    const int m = (int)blockIdx.x >> 6;   // 0=sem, 1=dst

    float v[9]; int ix[9];
    #pragma unroll
    for (int k = 0; k < 9; ++k) { v[k] = -INFINITY; ix[k] = 0x7fffffff; }

    const size_t roff = (size_t)b * NDB;
    for (int i = tid; i < NDB; i += 256) {
        float sval;
        if (m == 0) {
            const float s = semp0[roff + i] + semp1[roff + i];
            sval = s * (1.0f / sqrtf(nsq0[i] + nsq1[i]));
        } else {
            sval = dstp[roff + i] * (1.0f / sqrtf(nsqd[i]));
        }
        if (sval > v[0]) {
            bool bt[9];
            bt[0] = true;
            #pragma unroll
            for (int j = 1; j < 9; ++j) bt[j] = sval > v[j];
            #pragma unroll
            for (int j = 0; j < 8; ++j) {
                v[j]  = bt[j+1] ? v[j+1]  : (bt[j] ? sval : v[j]);
                ix[j] = bt[j+1] ? ix[j+1] : (bt[j] ? i    : ix[j]);
            }
            v[8]  = bt[8] ? sval : v[8];
            ix[8] = bt[8] ? i    : ix[8];
        }
    }

    #pragma unroll
    for (int k = 0; k < 9; ++k) { sv[tid][k] = v[k]; si[tid][k] = ix[k]; }
    __syncthreads();

    for (int s2 = 128; s2 >= 1; s2 >>= 1) {
        if (tid < s2) {
            float rv[9]; int ri[9];
            int pa = 8, pb = 8;
            #pragma unroll
            for (int k = 8; k >= 0; --k) {
                const float va = sv[tid][pa];      const int ia = si[tid][pa];
                const float vb = sv[tid + s2][pb]; const int ib = si[tid + s2][pb];
                const bool takeA = (va > vb) || (va == vb && ia < ib);
                rv[k] = takeA ? va : vb;
                ri[k] = takeA ? ia : ib;
                if (takeA) --pa; else --pb;
            }
            #pragma unroll
            for (int k = 0; k < 9; ++k) { sv[tid][k] = rv[k]; si[tid][k] = ri[k]; }
        }
        __syncthreads();
    }

    if (tid < 9) {
        const int idx = si[0][8 - tid];
        out_ret[(size_t)b * 18 + 2 * tid + m] = metrics[idx];
    }
}

__global__ void finalize_kernel(float* __restrict__ d_out)
{
    const int b = threadIdx.x;
    const float* r = d_out + 64 + (size_t)b * 18;
    float s = 0.f;
    #pragma unroll
    for (int j = 0; j < 18; ++j) s += r[j];
    d_out[b] = s * (1.0f / 18.0f);
}

extern "C" void kernel_launch(void* const* d_in, const int* in_sizes, int n_in,
                              void* d_out, int out_size, void* d_ws, size_t ws_size,
                              hipStream_t stream)
{
    const float* fc  = (const float*)d_in[0];   // [64][4096]
    const float* fd  = (const float*)d_in[1];   // [64][2048]
    const float* sdb = (const float*)d_in[2];   // [20000][4096]
    const float* ddb = (const float*)d_in[3];   // [20000][2048]
    const float* met = (const float*)d_in[4];   // [20000]

    float* semp0 = (float*)d_ws;
    float* semp1 = semp0 + (size_t)NQ * NDB;
    float* dstp  = semp1 + (size_t)NQ * NDB;
    float* nsq0  = dstp  + (size_t)NQ * NDB;
    float* nsq1  = nsq0 + NDB;
    float* nsqd  = nsq1 + NDB;
    _Float16* apack_sem = (_Float16*)(nsqd + NDB);           // 64*4096*2 halves
    _Float16* apack_dst = apack_sem + (size_t)NQ * KSEM * 2; // 64*2048*2 halves

    float* out = (float*)d_out;

    qsplit_kernel<<<dim3(192), dim3(256), 0, stream>>>(fc, fd, apack_sem, apack_dst);
    score_kernel<<<dim3(3 * NTILE), dim3(128), 0, stream>>>(
        sdb, ddb, apack_sem, apack_dst, semp0, semp1, dstp, nsq0, nsq1, nsqd);
    topk_kernel<<<dim3(128), dim3(256), 0, stream>>>(
        semp0, semp1, dstp, nsq0, nsq1, nsqd, met, out + 64);
    finalize_kernel<<<dim3(1), dim3(64), 0, stream>>>(out);
}

// Round 5
// 222.830 us; speedup vs baseline: 2.3571x; 1.2094x over previous
//
#include <hip/hip_runtime.h>
#include <math.h>

// NoRefRetIQANet: cosine top-K retrieval via fp16 2-split MFMA.
//   score[b,n] = dot(q_b, d_n) / ||d_n||  (query norm skipped: order-invariant)
//   x = hi + lo/4096;  dot = hh + (hl + lh)/4096  (ll term ~2^-24, dropped)
// Round-5: counted-vmcnt pipeline (T3+T4). 256 thr / 4 waves, 64q x 64n,
// K-step 32, 4-deep LDS ring (64 KB), prefetch distance 3, raw s_barrier +
// s_waitcnt vmcnt(8) -- loads never drain in the loop. A staged via
// global_load_lds from pre-split swizzled pack; B staged as RAW f32 via
// global_load_lds with source-side chunk swizzle (c' = c ^ (row&7));
// B->f16 hi/lo conversion at fragment-read time (norms folded in).
// ws: semp0[64][20000] f32, semp1, dstp, nsq0/1/d[20000], apack_sem, apack_dst
// d_out: [0,64) result, [64, 64+64*18) retrieved.

typedef _Float16 half8 __attribute__((ext_vector_type(8)));
typedef float    f32x4 __attribute__((ext_vector_type(4)));

#define NDB   20000
#define NQ    64
#define KSEM  4096
#define KDST  2048
#define KC    2048
#define NSTEP (KC / 32)     // 64
#define BN    64
#define NTILE 313           // ceil(20000/64); last tile row-clamped

__device__ __forceinline__ void async_cp16(const void* g, void* l) {
    __builtin_amdgcn_global_load_lds(
        (const __attribute__((address_space(1))) void*)g,
        (__attribute__((address_space(3))) void*)l, 16, 0, 0);
}

// ---------------------------------------------------------------------------
// qsplit: fp32 queries -> fragment-ordered, bank-swizzled f16 hi/lo pack.
// Unit u (16B = half8) within a 32-k step: u = 4*row + (((row>>1)&3)^kg);
// step section = 512 units: [0,256) hi, [256,512) lo.  (verified rounds 3-4)
// ---------------------------------------------------------------------------
__global__ __launch_bounds__(256) void qsplit_kernel(
    const float* __restrict__ fc, const float* __restrict__ fd,
    _Float16* __restrict__ apack_sem, _Float16* __restrict__ apack_dst)
{
    const int idx = (int)blockIdx.x * 256 + (int)threadIdx.x;
    const int NSEM8 = NQ * KSEM / 8;            // 32768
    const float* src; _Float16* dst; int row, g8, K;
    if (idx < NSEM8) { src = fc; dst = apack_sem; K = KSEM; row = idx >> 9; g8 = idx & 511; }
    else { const int j = idx - NSEM8; src = fd; dst = apack_dst; K = KDST; row = j >> 8; g8 = j & 255; }

    const float* p = src + (size_t)row * K + g8 * 8;
    const float4 v0 = ((const float4*)p)[0];
    const float4 v1 = ((const float4*)p)[1];
    const float xs[8] = {v0.x, v0.y, v0.z, v0.w, v1.x, v1.y, v1.z, v1.w};
    half8 hi, lo;
    #pragma unroll
    for (int e = 0; e < 8; ++e) {
        const _Float16 h = (_Float16)xs[e];
        hi[e] = h;
        lo[e] = (_Float16)((xs[e] - (float)h) * 4096.0f);
    }
    const int step = g8 >> 2, kg = g8 & 3;
    const int u = (row << 2) + (((row >> 1) & 3) ^ kg);
    half8* d8 = (half8*)dst;
    d8[step * 512 + u]       = hi;
    d8[step * 512 + 256 + u] = lo;
}

// ---------------------------------------------------------------------------
// score: 939 blocks = 313 n-tiles x {sem kc0, sem kc1, dst}, uniform KC=2048.
// Wave grid 2x2: wave w -> (qh=w>>1: q-rows qh*32+..., nh=w&1: n-cols nh*32+...).
// ---------------------------------------------------------------------------
__global__ __launch_bounds__(256, 2) void score_kernel(
    const float* __restrict__ sdb, const float* __restrict__ ddb,
    const _Float16* __restrict__ apack_sem, const _Float16* __restrict__ apack_dst,
    float* __restrict__ semp0, float* __restrict__ semp1, float* __restrict__ dstp,
    float* __restrict__ nsq0, float* __restrict__ nsq1, float* __restrict__ nsqd)
{
    __shared__ __align__(16) _Float16 A_lds[4][4096];   // 4 bufs x 512 units, 32 KB
    __shared__ __align__(16) float    B_lds[4][2048];   // 4 bufs x 512 units, 32 KB

    const int tid  = threadIdx.x;
    const int lane = tid & 63, w = tid >> 6;
    const int bid  = (int)blockIdx.x;
    const int mkc  = bid / NTILE;         // 0: sem kc0, 1: sem kc1, 2: dst
    const int nt   = bid % NTILE;
    const int n0   = nt * BN;

    const float* D; const _Float16* AP; float *SOUT, *NOUT; int Ks, koff;
    if (mkc == 0)      { D=sdb; AP=apack_sem; SOUT=semp0; NOUT=nsq0; Ks=KSEM; koff=0;  }
    else if (mkc == 1) { D=sdb; AP=apack_sem; SOUT=semp1; NOUT=nsq1; Ks=KSEM; koff=KC; }
    else               { D=ddb; AP=apack_dst; SOUT=dstp;  NOUT=nsqd; Ks=KDST; koff=0;  }

    // --- staging maps (per-thread constants) ---
    // Each thread DMAs units U1 (low half) and U2=U1+256 (high half) of both
    // the A step-section (512 units) and the B step-section (512 units).
    const int U1 = w * 64 + lane;                  // [0,256)
    const int r1 = U1 >> 3, c1 = (U1 & 7) ^ (r1 & 7);
    const int U2 = U1 + 256;
    const int r2 = U2 >> 3, c2 = (U2 & 7) ^ (r2 & 7);
    const int rg1 = (n0 + r1 < NDB) ? n0 + r1 : NDB - 1;   // clamp tail tile
    const int rg2 = (n0 + r2 < NDB) ? n0 + r2 : NDB - 1;
    const float* gB1 = D + (size_t)rg1 * Ks + koff + c1 * 4;
    const float* gB2 = D + (size_t)rg2 * Ks + koff + c2 * 4;
    const uint4* gA1 = (const uint4*)AP + ((size_t)koff >> 5) * 512 + U1;
    const uint4* gA2 = gA1 + 256;

    // --- compute map ---
    const int lr = lane & 15, kg = lane >> 4;
    const int qh = w >> 1, nh = w & 1;
    // A fragment unit offsets (halves), constant per thread:
    const int rowA0 = qh * 32 + 0 * 16 + lr;
    const int rowA1 = qh * 32 + 1 * 16 + lr;
    const int offA0 = ((rowA0 << 2) + (((rowA0 >> 1) & 3) ^ kg)) * 8;
    const int offA1 = ((rowA1 << 2) + (((rowA1 >> 1) & 3) ^ kg)) * 8;
    // B fragment float offsets (chunk-swizzled), constant per thread:
    const int rB0 = nh * 32 + 0 * 16 + lr;
    const int rB1 = nh * 32 + 1 * 16 + lr;
    const int offB00 = rB0 * 32 + (((kg * 2 + 0) ^ (rB0 & 7)) << 2);
    const int offB01 = rB0 * 32 + (((kg * 2 + 1) ^ (rB0 & 7)) << 2);
    const int offB10 = rB1 * 32 + (((kg * 2 + 0) ^ (rB1 & 7)) << 2);
    const int offB11 = rB1 * 32 + (((kg * 2 + 1) ^ (rB1 & 7)) << 2);

    f32x4 acc_h[2][2], acc_x[2][2];
    const f32x4 zz = {0.f, 0.f, 0.f, 0.f};
    #pragma unroll
    for (int i = 0; i < 2; ++i)
        #pragma unroll
        for (int j = 0; j < 2; ++j) { acc_h[i][j] = zz; acc_x[i][j] = zz; }
    float sq0 = 0.f, sq1 = 0.f;

    auto STAGE = [&](int s, int buf) {
        async_cp16(gA1 + (size_t)s * 512, &A_lds[buf][w * 512]);
        async_cp16(gA2 + (size_t)s * 512, &A_lds[buf][2048 + w * 512]);
        async_cp16(gB1 + (size_t)s * 32,  &B_lds[buf][w * 256]);
        async_cp16(gB2 + (size_t)s * 32,  &B_lds[buf][1024 + w * 256]);
    };

    auto COMPUTE = [&](int buf) {
        const float*    Bb = &B_lds[buf][0];
        const _Float16* Ab = &A_lds[buf][0];
        half8 bh0, bl0, bh1, bl1;
        {   // j = 0
            const f32x4 p = *(const f32x4*)(Bb + offB00);
            const f32x4 q = *(const f32x4*)(Bb + offB01);
            const float xs[8] = {p[0], p[1], p[2], p[3], q[0], q[1], q[2], q[3]};
            #pragma unroll
            for (int e = 0; e < 8; ++e) {
                const float x = xs[e];
                sq0 = fmaf(x, x, sq0);
                const _Float16 h = (_Float16)x;
                bh0[e] = h;
                bl0[e] = (_Float16)((x - (float)h) * 4096.0f);
            }
        }
        {   // j = 1
            const f32x4 p = *(const f32x4*)(Bb + offB10);
            const f32x4 q = *(const f32x4*)(Bb + offB11);
            const float xs[8] = {p[0], p[1], p[2], p[3], q[0], q[1], q[2], q[3]};
            #pragma unroll
            for (int e = 0; e < 8; ++e) {
                const float x = xs[e];
                sq1 = fmaf(x, x, sq1);
                const _Float16 h = (_Float16)x;
                bh1[e] = h;
                bl1[e] = (_Float16)((x - (float)h) * 4096.0f);
            }
        }
        const half8 ah0 = *(const half8*)(Ab + offA0);
        const half8 av0 = *(const half8*)(Ab + 2048 + offA0);
        const half8 ah1 = *(const half8*)(Ab + offA1);
        const half8 av1 = *(const half8*)(Ab + 2048 + offA1);

        acc_h[0][0] = __builtin_amdgcn_mfma_f32_16x16x32_f16(ah0, bh0, acc_h[0][0], 0, 0, 0);
        acc_x[0][0] = __builtin_amdgcn_mfma_f32_16x16x32_f16(ah0, bl0, acc_x[0][0], 0, 0, 0);
        acc_x[0][0] = __builtin_amdgcn_mfma_f32_16x16x32_f16(av0, bh0, acc_x[0][0], 0, 0, 0);
        acc_h[0][1] = __builtin_amdgcn_mfma_f32_16x16x32_f16(ah0, bh1, acc_h[0][1], 0, 0, 0);
        acc_x[0][1] = __builtin_amdgcn_mfma_f32_16x16x32_f16(ah0, bl1, acc_x[0][1], 0, 0, 0);
        acc_x[0][1] = __builtin_amdgcn_mfma_f32_16x16x32_f16(av0, bh1, acc_x[0][1], 0, 0, 0);
        acc_h[1][0] = __builtin_amdgcn_mfma_f32_16x16x32_f16(ah1, bh0, acc_h[1][0], 0, 0, 0);
        acc_x[1][0] = __builtin_amdgcn_mfma_f32_16x16x32_f16(ah1, bl0, acc_x[1][0], 0, 0, 0);
        acc_x[1][0] = __builtin_amdgcn_mfma_f32_16x16x32_f16(av1, bh0, acc_x[1][0], 0, 0, 0);
        acc_h[1][1] = __builtin_amdgcn_mfma_f32_16x16x32_f16(ah1, bh1, acc_h[1][1], 0, 0, 0);
        acc_x[1][1] = __builtin_amdgcn_mfma_f32_16x16x32_f16(ah1, bl1, acc_x[1][1], 0, 0, 0);
        acc_x[1][1] = __builtin_amdgcn_mfma_f32_16x16x32_f16(av1, bh1, acc_x[1][1], 0, 0, 0);
    };

    // prologue: 3 steps in flight (12 outstanding DMAs per wave)
    STAGE(0, 0); STAGE(1, 1); STAGE(2, 2);

    for (int s = 0; s < NSTEP; ++s) {
        // wait for step-s DMAs (this wave's 4), keep s+1..s+3 in flight
        if (s < NSTEP - 2)       { asm volatile("s_waitcnt vmcnt(8)" ::: "memory"); }
        else if (s == NSTEP - 2) { asm volatile("s_waitcnt vmcnt(4)" ::: "memory"); }
        else                     { asm volatile("s_waitcnt vmcnt(0)" ::: "memory"); }
        __builtin_amdgcn_s_barrier();      // raw: no vmcnt(0) drain
        // all waves finished COMPUTE(s-1) at this barrier -> buf[(s+3)&3]
        // (== buf[(s-1)&3]) is safe to overwrite
        if (s + 3 < NSTEP) STAGE(s + 3, (s + 3) & 3);
        COMPUTE(s & 3);
    }

    // norms: each lane's sq covers (col = nh*32 + j*16 + lr, its kg k-slices);
    // reduce over kg (lanes +-16, +-32); identical across qh -> qh==0 writes.
    sq0 += __shfl_xor(sq0, 16); sq0 += __shfl_xor(sq0, 32);
    sq1 += __shfl_xor(sq1, 16); sq1 += __shfl_xor(sq1, 32);
    if (qh == 0 && lane < 16) {
        const int nn0 = n0 + nh * 32 + lane;
        const int nn1 = nn0 + 16;
        if (nn0 < NDB) NOUT[nn0] = sq0;
        if (nn1 < NDB) NOUT[nn1] = sq1;
    }

    // C/D map: col=lane&15, row=(lane>>4)*4+reg (m89-verified)
    #pragma unroll
    for (int i = 0; i < 2; ++i)
        #pragma unroll
        for (int j = 0; j < 2; ++j) {
            const int n = n0 + nh * 32 + j * 16 + lr;
            if (n < NDB) {
                #pragma unroll
                for (int rr = 0; rr < 4; ++rr) {
                    const int q = qh * 32 + i * 16 + kg * 4 + rr;
                    SOUT[(size_t)q * NDB + n] = acc_h[i][j][rr] + acc_x[i][j][rr] * (1.0f / 4096.0f);
                }
            }
        }
}

// ---------------------------------------------------------------------------
// Top-9 per (matrix m, row b); combines sem partials, applies 1/||d_n||.
// Comparator: value desc, index asc (matches lax.top_k).
// ---------------------------------------------------------------------------
__global__ __launch_bounds__(256) void topk_kernel(
    const float* __restrict__ semp0, const float* __restrict__ semp1,
    const float* __restrict__ dstp,
    const float* __restrict__ nsq0, const float* __restrict__ nsq1,
    const float* __restrict__ nsqd,
    const float* __restrict__ metrics, float* __restrict__ out_ret)
{
    __shared__ float sv[256][9];
    __shared__ int   si[256][9];

    const int tid = threadIdx.x;
    const int b = (int)blockIdx.x & 63;
    const int m = (int)blockIdx.x >> 6;   // 0=sem, 1=dst

    float v[9]; int ix[9];
    #pragma unroll
    for (int k = 0; k < 9; ++k) { v[k] = -INFINITY; ix[k] = 0x7fffffff; }

    const size_t roff = (size_t)b * NDB;
    for (int i = tid; i < NDB; i += 256) {
        float sval;
        if (m == 0) {
            const float s = semp0[roff + i] + semp1[roff + i];
            sval = s * (1.0f / sqrtf(nsq0[i] + nsq1[i]));
        } else {
            sval = dstp[roff + i] * (1.0f / sqrtf(nsqd[i]));
        }
        if (sval > v[0]) {
            bool bt[9];
            bt[0] = true;
            #pragma unroll
            for (int j = 1; j < 9; ++j) bt[j] = sval > v[j];
            #pragma unroll
            for (int j = 0; j < 8; ++j) {
                v[j]  = bt[j+1] ? v[j+1]  : (bt[j] ? sval : v[j]);
                ix[j] = bt[j+1] ? ix[j+1] : (bt[j] ? i    : ix[j]);
            }
            v[8]  = bt[8] ? sval : v[8];
            ix[8] = bt[8] ? i    : ix[8];
        }
    }

    #pragma unroll
    for (int k = 0; k < 9; ++k) { sv[tid][k] = v[k]; si[tid][k] = ix[k]; }
    __syncthreads();

    for (int s2 = 128; s2 >= 1; s2 >>= 1) {
        if (tid < s2) {
            float rv[9]; int ri[9];
            int pa = 8, pb = 8;
            #pragma unroll
            for (int k = 8; k >= 0; --k) {
                const float va = sv[tid][pa];      const int ia = si[tid][pa];
                const float vb = sv[tid + s2][pb]; const int ib = si[tid + s2][pb];
                const bool takeA = (va > vb) || (va == vb && ia < ib);
                rv[k] = takeA ? va : vb;
                ri[k] = takeA ? ia : ib;
                if (takeA) --pa; else --pb;
            }
            #pragma unroll
            for (int k = 0; k < 9; ++k) { sv[tid][k] = rv[k]; si[tid][k] = ri[k]; }
        }
        __syncthreads();
    }

    if (tid < 9) {
        const int idx = si[0][8 - tid];
        out_ret[(size_t)b * 18 + 2 * tid + m] = metrics[idx];
    }
}

__global__ void finalize_kernel(float* __restrict__ d_out)
{
    const int b = threadIdx.x;
    const float* r = d_out + 64 + (size_t)b * 18;
    float s = 0.f;
    #pragma unroll
    for (int j = 0; j < 18; ++j) s += r[j];
    d_out[b] = s * (1.0f / 18.0f);
}

extern "C" void kernel_launch(void* const* d_in, const int* in_sizes, int n_in,
                              void* d_out, int out_size, void* d_ws, size_t ws_size,
                              hipStream_t stream)
{
    const float* fc  = (const float*)d_in[0];   // [64][4096]
    const float* fd  = (const float*)d_in[1];   // [64][2048]
    const float* sdb = (const float*)d_in[2];   // [20000][4096]
    const float* ddb = (const float*)d_in[3];   // [20000][2048]
    const float* met = (const float*)d_in[4];   // [20000]

    float* semp0 = (float*)d_ws;
    float* semp1 = semp0 + (size_t)NQ * NDB;
    float* dstp  = semp1 + (size_t)NQ * NDB;
    float* nsq0  = dstp  + (size_t)NQ * NDB;
    float* nsq1  = nsq0 + NDB;
    float* nsqd  = nsq1 + NDB;
    _Float16* apack_sem = (_Float16*)(nsqd + NDB);           // 1 MB
    _Float16* apack_dst = apack_sem + (size_t)NQ * KSEM * 2; // 0.5 MB

    float* out = (float*)d_out;

    qsplit_kernel<<<dim3(192), dim3(256), 0, stream>>>(fc, fd, apack_sem, apack_dst);
    score_kernel<<<dim3(3 * NTILE), dim3(256), 0, stream>>>(
        sdb, ddb, apack_sem, apack_dst, semp0, semp1, dstp, nsq0, nsq1, nsqd);
    topk_kernel<<<dim3(128), dim3(256), 0, stream>>>(
        semp0, semp1, dstp, nsq0, nsq1, nsqd, met, out + 64);
    finalize_kernel<<<dim3(1), dim3(64), 0, stream>>>(out);
}

// Round 6
// 183.039 us; speedup vs baseline: 2.8695x; 1.2174x over previous
//
#include <hip/hip_runtime.h>
#include <math.h>

// NoRefRetIQANet: cosine top-K retrieval via fp16 2-split MFMA.
//   score[b,n] = dot(q_b, d_n) / ||d_n||  (query norm skipped: order-invariant)
//   x = hi + lo/4096;  dot = hh + (hl + lh)/4096  (ll term ~2^-24, dropped)
// Round-6: K-step 64 (two 32-K sections per step) -> 32 steps/block,
// 30K block-steps / 512 slots = 59 serial step-times (vs 117 in round 5).
// Ring 2 x 32 KB, counted vmcnt(8) gate, raw barriers, stage-after-compute.
// A staged via global_load_lds from pre-split swizzled pack; B staged raw f32
// via global_load_lds with source-side chunk swizzle; B->f16 hi/lo at read.
// ws: semp0[64][20000] f32, semp1, dstp, nsq0/1/d[20000], apack_sem, apack_dst
// d_out: [0,64) result, [64, 64+64*18) retrieved.

typedef _Float16 half8 __attribute__((ext_vector_type(8)));
typedef float    f32x4 __attribute__((ext_vector_type(4)));

#define NDB   20000
#define NQ    64
#define KSEM  4096
#define KDST  2048
#define KC    2048
#define NSTEP (KC / 64)     // 32 steps of 64
#define BN    64
#define NTILE 313           // ceil(20000/64); last tile row-clamped

__device__ __forceinline__ void async_cp16(const void* g, void* l) {
    __builtin_amdgcn_global_load_lds(
        (const __attribute__((address_space(1))) void*)g,
        (__attribute__((address_space(3))) void*)l, 16, 0, 0);
}

// ---------------------------------------------------------------------------
// qsplit: fp32 queries -> fragment-ordered, bank-swizzled f16 hi/lo pack.
// Unit u (16B = half8) within a 32-k section: u = 4*row + (((row>>1)&3)^kg);
// section = 512 units: [0,256) hi, [256,512) lo.  (verified rounds 3-5)
// ---------------------------------------------------------------------------
__global__ __launch_bounds__(256) void qsplit_kernel(
    const float* __restrict__ fc, const float* __restrict__ fd,
    _Float16* __restrict__ apack_sem, _Float16* __restrict__ apack_dst)
{
    const int idx = (int)blockIdx.x * 256 + (int)threadIdx.x;
    const int NSEM8 = NQ * KSEM / 8;            // 32768
    const float* src; _Float16* dst; int row, g8, K;
    if (idx < NSEM8) { src = fc; dst = apack_sem; K = KSEM; row = idx >> 9; g8 = idx & 511; }
    else { const int j = idx - NSEM8; src = fd; dst = apack_dst; K = KDST; row = j >> 8; g8 = j & 255; }

    const float* p = src + (size_t)row * K + g8 * 8;
    const float4 v0 = ((const float4*)p)[0];
    const float4 v1 = ((const float4*)p)[1];
    const float xs[8] = {v0.x, v0.y, v0.z, v0.w, v1.x, v1.y, v1.z, v1.w};
    half8 hi, lo;
    #pragma unroll
    for (int e = 0; e < 8; ++e) {
        const _Float16 h = (_Float16)xs[e];
        hi[e] = h;
        lo[e] = (_Float16)((xs[e] - (float)h) * 4096.0f);
    }
    const int sec = g8 >> 2, kg = g8 & 3;
    const int u = (row << 2) + (((row >> 1) & 3) ^ kg);
    half8* d8 = (half8*)dst;
    d8[sec * 512 + u]       = hi;
    d8[sec * 512 + 256 + u] = lo;
}

// ---------------------------------------------------------------------------
// score: 939 blocks = 313 n-tiles x {sem kc0, sem kc1, dst}, uniform KC=2048.
// 256 thr / 4 waves, wave grid 2x2 (qh=w>>1, nh=w&1), each 32q x 32n.
// ---------------------------------------------------------------------------
__global__ __launch_bounds__(256, 2) void score_kernel(
    const float* __restrict__ sdb, const float* __restrict__ ddb,
    const _Float16* __restrict__ apack_sem, const _Float16* __restrict__ apack_dst,
    float* __restrict__ semp0, float* __restrict__ semp1, float* __restrict__ dstp,
    float* __restrict__ nsq0, float* __restrict__ nsq1, float* __restrict__ nsqd)
{
    // [buf][sec*4096 + q*2048 + u*8]: sec in {0,1} 32-K sections, q=hi/lo
    __shared__ __align__(16) _Float16 A_lds[2][8192];   // 32 KB
    // [buf][sec*2048 + r*32 + c*4]: chunk c XOR-swizzled by row
    __shared__ __align__(16) float    B_lds[2][4096];   // 32 KB

    const int tid  = threadIdx.x;
    const int lane = tid & 63, w = tid >> 6;
    const int bid  = (int)blockIdx.x;
    const int mkc  = bid / NTILE;         // 0: sem kc0, 1: sem kc1, 2: dst
    const int nt   = bid % NTILE;
    const int n0   = nt * BN;

    const float* D; const _Float16* AP; float *SOUT, *NOUT; int Ks, koff;
    if (mkc == 0)      { D=sdb; AP=apack_sem; SOUT=semp0; NOUT=nsq0; Ks=KSEM; koff=0;  }
    else if (mkc == 1) { D=sdb; AP=apack_sem; SOUT=semp1; NOUT=nsq1; Ks=KSEM; koff=KC; }
    else               { D=ddb; AP=apack_dst; SOUT=dstp;  NOUT=nsqd; Ks=KDST; koff=0;  }

    // --- staging maps ---
    // B: per wave, 2 unit-groups per section: u = w*128 + g*64 + lane
    const int u0 = w * 128 + lane,      r0 = u0 >> 3, c0 = (u0 & 7) ^ (r0 & 7);
    const int u1 = u0 + 64,             r1 = u1 >> 3, c1 = (u1 & 7) ^ (r1 & 7);
    const int rg0 = (n0 + r0 < NDB) ? n0 + r0 : NDB - 1;   // clamp tail tile
    const int rg1 = (n0 + r1 < NDB) ? n0 + r1 : NDB - 1;
    const float* gB0 = D + (size_t)rg0 * Ks + koff + c0 * 4;
    const float* gB1 = D + (size_t)rg1 * Ks + koff + c1 * 4;
    // A: per wave, per (sec, q): units q*256 + w*64 + lane of section 2s+sec
    const uint4* gA = (const uint4*)AP + ((size_t)koff >> 5) * 512 + w * 64 + lane;

    // --- compute map ---
    const int lr = lane & 15, kg = lane >> 4;
    const int qh = w >> 1, nh = w & 1;
    const int rowA0 = qh * 32 + lr;
    const int rowA1 = rowA0 + 16;
    const int uA0 = ((rowA0 << 2) + (((rowA0 >> 1) & 3) ^ kg)) * 8;
    const int uA1 = ((rowA1 << 2) + (((rowA1 >> 1) & 3) ^ kg)) * 8;
    const int rB0 = nh * 32 + lr;
    const int rB1 = rB0 + 16;
    const int oB00 = rB0 * 32 + (((kg * 2 + 0) ^ (rB0 & 7)) << 2);
    const int oB01 = rB0 * 32 + (((kg * 2 + 1) ^ (rB0 & 7)) << 2);
    const int oB10 = rB1 * 32 + (((kg * 2 + 0) ^ (rB1 & 7)) << 2);
    const int oB11 = rB1 * 32 + (((kg * 2 + 1) ^ (rB1 & 7)) << 2);

    f32x4 acc_h[2][2], acc_x[2][2];
    const f32x4 zz = {0.f, 0.f, 0.f, 0.f};
    #pragma unroll
    for (int i = 0; i < 2; ++i)
        #pragma unroll
        for (int j = 0; j < 2; ++j) { acc_h[i][j] = zz; acc_x[i][j] = zz; }
    float sq0 = 0.f, sq1 = 0.f;

    auto STAGE = [&](int s, int buf) {
        #pragma unroll
        for (int sec = 0; sec < 2; ++sec) {
            const size_t gsec = (size_t)(2 * s + sec);
            // A: hi quarter + lo quarter for this wave
            async_cp16(gA + gsec * 512,       &A_lds[buf][sec * 4096 + w * 512]);
            async_cp16(gA + gsec * 512 + 256, &A_lds[buf][sec * 4096 + 2048 + w * 512]);
            // B: two unit-groups
            async_cp16(gB0 + gsec * 32, &B_lds[buf][sec * 2048 + w * 512]);
            async_cp16(gB1 + gsec * 32, &B_lds[buf][sec * 2048 + w * 512 + 256]);
        }
    };

    auto COMPUTE = [&](int buf) {
        #pragma unroll
        for (int sec = 0; sec < 2; ++sec) {
            const float*    Bb = &B_lds[buf][sec * 2048];
            const _Float16* Ab = &A_lds[buf][sec * 4096];
            half8 bh0, bl0, bh1, bl1;
            {   // j = 0
                const f32x4 p = *(const f32x4*)(Bb + oB00);
                const f32x4 q = *(const f32x4*)(Bb + oB01);
                const float xs[8] = {p[0], p[1], p[2], p[3], q[0], q[1], q[2], q[3]};
                #pragma unroll
                for (int e = 0; e < 8; ++e) {
                    const float x = xs[e];
                    sq0 = fmaf(x, x, sq0);
                    const _Float16 h = (_Float16)x;
                    bh0[e] = h;
                    bl0[e] = (_Float16)((x - (float)h) * 4096.0f);
                }
            }
            {   // j = 1
                const f32x4 p = *(const f32x4*)(Bb + oB10);
                const f32x4 q = *(const f32x4*)(Bb + oB11);
                const float xs[8] = {p[0], p[1], p[2], p[3], q[0], q[1], q[2], q[3]};
                #pragma unroll
                for (int e = 0; e < 8; ++e) {
                    const float x = xs[e];
                    sq1 = fmaf(x, x, sq1);
                    const _Float16 h = (_Float16)x;
                    bh1[e] = h;
                    bl1[e] = (_Float16)((x - (float)h) * 4096.0f);
                }
            }
            const half8 ah0 = *(const half8*)(Ab + uA0);
            const half8 av0 = *(const half8*)(Ab + 2048 + uA0);
            const half8 ah1 = *(const half8*)(Ab + uA1);
            const half8 av1 = *(const half8*)(Ab + 2048 + uA1);

            acc_h[0][0] = __builtin_amdgcn_mfma_f32_16x16x32_f16(ah0, bh0, acc_h[0][0], 0, 0, 0);
            acc_x[0][0] = __builtin_amdgcn_mfma_f32_16x16x32_f16(ah0, bl0, acc_x[0][0], 0, 0, 0);
            acc_x[0][0] = __builtin_amdgcn_mfma_f32_16x16x32_f16(av0, bh0, acc_x[0][0], 0, 0, 0);
            acc_h[0][1] = __builtin_amdgcn_mfma_f32_16x16x32_f16(ah0, bh1, acc_h[0][1], 0, 0, 0);
            acc_x[0][1] = __builtin_amdgcn_mfma_f32_16x16x32_f16(ah0, bl1, acc_x[0][1], 0, 0, 0);
            acc_x[0][1] = __builtin_amdgcn_mfma_f32_16x16x32_f16(av0, bh1, acc_x[0][1], 0, 0, 0);
            acc_h[1][0] = __builtin_amdgcn_mfma_f32_16x16x32_f16(ah1, bh0, acc_h[1][0], 0, 0, 0);
            acc_x[1][0] = __builtin_amdgcn_mfma_f32_16x16x32_f16(ah1, bl0, acc_x[1][0], 0, 0, 0);
            acc_x[1][0] = __builtin_amdgcn_mfma_f32_16x16x32_f16(av1, bh0, acc_x[1][0], 0, 0, 0);
            acc_h[1][1] = __builtin_amdgcn_mfma_f32_16x16x32_f16(ah1, bh1, acc_h[1][1], 0, 0, 0);
            acc_x[1][1] = __builtin_amdgcn_mfma_f32_16x16x32_f16(ah1, bl1, acc_x[1][1], 0, 0, 0);
            acc_x[1][1] = __builtin_amdgcn_mfma_f32_16x16x32_f16(av1, bh1, acc_x[1][1], 0, 0, 0);
        }
    };

    // prologue: 2 steps staged (16 DMAs/wave outstanding)
    STAGE(0, 0); STAGE(1, 1);

    for (int s = 0; s < NSTEP; ++s) {
        // wait this step's 8 DMAs; keep next step's 8 in flight
        if (s < NSTEP - 1) { asm volatile("s_waitcnt vmcnt(8)" ::: "memory"); }
        else               { asm volatile("s_waitcnt vmcnt(0)" ::: "memory"); }
        __builtin_amdgcn_s_barrier();      // data(s) visible to all waves
        COMPUTE(s & 1);
        __builtin_amdgcn_s_barrier();      // all waves done reading buf s&1
        if (s + 2 < NSTEP) STAGE(s + 2, s & 1);
    }

    // norms: lane's sq covers (col = nh*32 + {lr, lr+16}, its kg k-slices);
    // reduce over kg (lanes +-16, +-32); identical across qh -> qh==0 writes.
    sq0 += __shfl_xor(sq0, 16); sq0 += __shfl_xor(sq0, 32);
    sq1 += __shfl_xor(sq1, 16); sq1 += __shfl_xor(sq1, 32);
    if (qh == 0 && lane < 16) {
        const int nn0 = n0 + nh * 32 + lane;
        const int nn1 = nn0 + 16;
        if (nn0 < NDB) NOUT[nn0] = sq0;
        if (nn1 < NDB) NOUT[nn1] = sq1;
    }

    // C/D map: col=lane&15, row=(lane>>4)*4+reg (m89-verified)
    #pragma unroll
    for (int i = 0; i < 2; ++i)
        #pragma unroll
        for (int j = 0; j < 2; ++j) {
            const int n = n0 + nh * 32 + j * 16 + lr;
            if (n < NDB) {
                #pragma unroll
                for (int rr = 0; rr < 4; ++rr) {
                    const int q = qh * 32 + i * 16 + kg * 4 + rr;
                    SOUT[(size_t)q * NDB + n] = acc_h[i][j][rr] + acc_x[i][j][rr] * (1.0f / 4096.0f);
                }
            }
        }
}

// ---------------------------------------------------------------------------
// Top-9 per (matrix m, row b); combines sem partials, applies 1/||d_n||.
// Comparator: value desc, index asc (matches lax.top_k).
// ---------------------------------------------------------------------------
__global__ __launch_bounds__(256) void topk_kernel(
    const float* __restrict__ semp0, const float* __restrict__ semp1,
    const float* __restrict__ dstp,
    const float* __restrict__ nsq0, const float* __restrict__ nsq1,
    const float* __restrict__ nsqd,
    const float* __restrict__ metrics, float* __restrict__ out_ret)
{
    __shared__ float sv[256][9];
    __shared__ int   si[256][9];

    const int tid = threadIdx.x;
    const int b = (int)blockIdx.x & 63;
    const int m = (int)blockIdx.x >> 6;   // 0=sem, 1=dst

    float v[9]; int ix[9];
    #pragma unroll
    for (int k = 0; k < 9; ++k) { v[k] = -INFINITY; ix[k] = 0x7fffffff; }

    const size_t roff = (size_t)b * NDB;
    for (int i = tid; i < NDB; i += 256) {
        float sval;
        if (m == 0) {
            const float s = semp0[roff + i] + semp1[roff + i];
            sval = s * (1.0f / sqrtf(nsq0[i] + nsq1[i]));
        } else {
            sval = dstp[roff + i] * (1.0f / sqrtf(nsqd[i]));
        }
        if (sval > v[0]) {
            bool bt[9];
            bt[0] = true;
            #pragma unroll
            for (int j = 1; j < 9; ++j) bt[j] = sval > v[j];
            #pragma unroll
            for (int j = 0; j < 8; ++j) {
                v[j]  = bt[j+1] ? v[j+1]  : (bt[j] ? sval : v[j]);
                ix[j] = bt[j+1] ? ix[j+1] : (bt[j] ? i    : ix[j]);
            }
            v[8]  = bt[8] ? sval : v[8];
            ix[8] = bt[8] ? i    : ix[8];
        }
    }

    #pragma unroll
    for (int k = 0; k < 9; ++k) { sv[tid][k] = v[k]; si[tid][k] = ix[k]; }
    __syncthreads();

    for (int s2 = 128; s2 >= 1; s2 >>= 1) {
        if (tid < s2) {
            float rv[9]; int ri[9];
            int pa = 8, pb = 8;
            #pragma unroll
            for (int k = 8; k >= 0; --k) {
                const float va = sv[tid][pa];      const int ia = si[tid][pa];
                const float vb = sv[tid + s2][pb]; const int ib = si[tid + s2][pb];
                const bool takeA = (va > vb) || (va == vb && ia < ib);
                rv[k] = takeA ? va : vb;
                ri[k] = takeA ? ia : ib;
                if (takeA) --pa; else --pb;
            }
            #pragma unroll
            for (int k = 0; k < 9; ++k) { sv[tid][k] = rv[k]; si[tid][k] = ri[k]; }
        }
        __syncthreads();
    }

    if (tid < 9) {
        const int idx = si[0][8 - tid];
        out_ret[(size_t)b * 18 + 2 * tid + m] = metrics[idx];
    }
}

__global__ void finalize_kernel(float* __restrict__ d_out)
{
    const int b = threadIdx.x;
    const float* r = d_out + 64 + (size_t)b * 18;
    float s = 0.f;
    #pragma unroll
    for (int j = 0; j < 18; ++j) s += r[j];
    d_out[b] = s * (1.0f / 18.0f);
}

extern "C" void kernel_launch(void* const* d_in, const int* in_sizes, int n_in,
                              void* d_out, int out_size, void* d_ws, size_t ws_size,
                              hipStream_t stream)
{
    const float* fc  = (const float*)d_in[0];   // [64][4096]
    const float* fd  = (const float*)d_in[1];   // [64][2048]
    const float* sdb = (const float*)d_in[2];   // [20000][4096]
    const float* ddb = (const float*)d_in[3];   // [20000][2048]
    const float* met = (const float*)d_in[4];   // [20000]

    float* semp0 = (float*)d_ws;
    float* semp1 = semp0 + (size_t)NQ * NDB;
    float* dstp  = semp1 + (size_t)NQ * NDB;
    float* nsq0  = dstp  + (size_t)NQ * NDB;
    float* nsq1  = nsq0 + NDB;
    float* nsqd  = nsq1 + NDB;
    _Float16* apack_sem = (_Float16*)(nsqd + NDB);           // 1 MB
    _Float16* apack_dst = apack_sem + (size_t)NQ * KSEM * 2; // 0.5 MB

    float* out = (float*)d_out;

    qsplit_kernel<<<dim3(192), dim3(256), 0, stream>>>(fc, fd, apack_sem, apack_dst);
    score_kernel<<<dim3(3 * NTILE), dim3(256), 0, stream>>>(
        sdb, ddb, apack_sem, apack_dst, semp0, semp1, dstp, nsq0, nsq1, nsqd);
    topk_kernel<<<dim3(128), dim3(256), 0, stream>>>(
        semp0, semp1, dstp, nsq0, nsq1, nsqd, met, out + 64);
    finalize_kernel<<<dim3(1), dim3(64), 0, stream>>>(out);
}